// Round 16
// baseline (340.199 us; speedup 1.0000x reference)
//
#include <hip/hip_runtime.h>

// B=2, L=S=2048, D_MODEL=1024, H=16, D_HEAD=64
// d_out = [out: 2*2048*1024 f32][A: 2*16*2048*2048 f32]

typedef __attribute__((ext_vector_type(8))) __bf16 bf16x8;
typedef __attribute__((ext_vector_type(4))) float f32x4;

__device__ __forceinline__ unsigned int f2bf_u(float f) {
  unsigned int u = __float_as_uint(f);
  return (u + 0x7FFFu + ((u >> 16) & 1u)) >> 16;  // RNE
}
__device__ __forceinline__ float bf2f(unsigned int h) {
  return __uint_as_float(h << 16);
}
__device__ __forceinline__ unsigned int pack2(float lo, float hi) {
  return (f2bf_u(hi) << 16) | f2bf_u(lo);
}
__device__ __forceinline__ f32x4 mfma16(bf16x8 a, bf16x8 b, f32x4 c) {
  return __builtin_amdgcn_mfma_f32_16x16x32_bf16(a, b, c, 0, 0, 0);
}
__device__ __forceinline__ void gll16(const void* g, void* l) {
  __builtin_amdgcn_global_load_lds(
      (const __attribute__((address_space(1))) unsigned int*)g,
      (__attribute__((address_space(3))) unsigned int*)l, 16, 0, 0);
}

// ---------------------------------------------------------------- transpose
// W[1024 in][1024 out] f32  ->  WT[1024 out][1024 in] bf16
__global__ __launch_bounds__(256) void transpose_w(
    const float* __restrict__ W0, const float* __restrict__ W1,
    const float* __restrict__ W2, const float* __restrict__ W3,
    unsigned short* __restrict__ T0, unsigned short* __restrict__ T1,
    unsigned short* __restrict__ T2, unsigned short* __restrict__ T3) {
  const float* W; unsigned short* T;
  switch (blockIdx.z) {
    case 0: W = W0; T = T0; break;
    case 1: W = W1; T = T1; break;
    case 2: W = W2; T = T2; break;
    default: W = W3; T = T3; break;
  }
  __shared__ float tile[32][33];
  const int tx = threadIdx.x, ty = threadIdx.y;  // 32 x 8
  const int i0 = blockIdx.x * 32, o0 = blockIdx.y * 32;
  #pragma unroll
  for (int r = 0; r < 4; ++r)
    tile[ty + 8 * r][tx] = W[(size_t)(i0 + ty + 8 * r) * 1024 + o0 + tx];
  __syncthreads();
  #pragma unroll
  for (int r = 0; r < 4; ++r)
    T[(size_t)(o0 + ty + 8 * r) * 1024 + i0 + tx] =
        (unsigned short)f2bf_u(tile[tx][ty + 8 * r]);
}

// ---------------------------------------------------------------- merged QKV GEMM
// One dispatch, grid (32, 8, 3): z selects {Q,K,V} job -> 768 WGs = 3 WG/CU.
// C[M,N] = A[M,K]*BT[N,K]^T + bias ; A f32 (converted in staging).
// Staging balanced across ALL 4 waves (A: 4 chunks/thread, B: 2 gll16/wave).
// omode (runtime, epilogue only): 0 = bf16 row-major C, 2 = bf16 VT[bh][d][s].
struct GemmJob {
  const float* A;
  const unsigned short* BT;
  const float* bias;
  void* C;
  int omode;
};
struct GemmJobs { GemmJob j[3]; };

__global__ __launch_bounds__(256) void gemm_qkv(GemmJobs jobs, int M, int N, int K) {
  const GemmJob jb = jobs.j[blockIdx.z];
  __shared__ unsigned short As[128][40];
  __shared__ unsigned short Bs[128][32];
  const int tid = threadIdx.x;
  const int lane = tid & 63, wid = tid >> 6;
  const int l15 = lane & 15, l4 = lane >> 4;
  const int m0 = blockIdx.x * 128, n0 = blockIdx.y * 128;
  const int wr = wid >> 1, wc = wid & 1;

  f32x4 acc[4][4];
  #pragma unroll
  for (int i = 0; i < 4; ++i)
    #pragma unroll
    for (int j = 0; j < 4; ++j) acc[i][j] = (f32x4){0.f, 0.f, 0.f, 0.f};

  const int nk = K >> 5;
  for (int kt = 0; kt < nk; ++kt) {
    // A f32 -> bf16: all 256 threads, 4 chunks each (chunk-coalesced 128B/row)
    #pragma unroll
    for (int c = 0; c < 4; ++c) {
      const int chunk = c * 256 + tid;
      const int row = chunk >> 3, col4 = chunk & 7;
      const float4 f = *(const float4*)(jb.A +
                                        (size_t)(m0 + row) * K + kt * 32 + col4 * 4);
      ushort4 o;
      o.x = (unsigned short)f2bf_u(f.x);
      o.y = (unsigned short)f2bf_u(f.y);
      o.z = (unsigned short)f2bf_u(f.z);
      o.w = (unsigned short)f2bf_u(f.w);
      *(ushort4*)&As[row][col4 * 4] = o;
    }
    // B bf16 via global_load_lds: all 4 waves, 2 calls each
    #pragma unroll
    for (int c = 0; c < 2; ++c) {
      const int off = wid * 2048 + c * 1024;
      const int loff = off + lane * 16;
      const int row = loff >> 6, colb = loff & 63;
      gll16(jb.BT + (size_t)(n0 + row) * K + kt * 32 + colb / 2,
            (char*)&Bs[0][0] + off);
    }
    __syncthreads();
    bf16x8 af[4], bfr[4];
    #pragma unroll
    for (int i = 0; i < 4; ++i)
      af[i] = *(const bf16x8*)&As[wr * 64 + i * 16 + l15][l4 * 8];
    #pragma unroll
    for (int j = 0; j < 4; ++j)
      bfr[j] = *(const bf16x8*)&Bs[wc * 64 + j * 16 + l15][l4 * 8];
    #pragma unroll
    for (int i = 0; i < 4; ++i)
      #pragma unroll
      for (int j = 0; j < 4; ++j)
        acc[i][j] = mfma16(af[i], bfr[j], acc[i][j]);
    __syncthreads();
  }

  #pragma unroll
  for (int j = 0; j < 4; ++j) {
    const int col = n0 + wc * 64 + j * 16 + l15;
    const float bv = jb.bias[col];
    #pragma unroll
    for (int i = 0; i < 4; ++i) {
      const int rowb = m0 + wr * 64 + i * 16 + l4 * 4;
      if (jb.omode == 2) {
        const int bq = rowb >> 11, sq = rowb & 2047;
        const int hq = col >> 6, dq = col & 63;
        ushort4 o;
        o.x = (unsigned short)f2bf_u(acc[i][j][0] + bv);
        o.y = (unsigned short)f2bf_u(acc[i][j][1] + bv);
        o.z = (unsigned short)f2bf_u(acc[i][j][2] + bv);
        o.w = (unsigned short)f2bf_u(acc[i][j][3] + bv);
        *(ushort4*)((unsigned short*)jb.C +
                    ((size_t)((bq * 16 + hq) * 64 + dq) << 11) + sq) = o;
      } else {
        #pragma unroll
        for (int q = 0; q < 4; ++q)
          ((unsigned short*)jb.C)[(size_t)(rowb + q) * N + col] =
              (unsigned short)f2bf_u(acc[i][j][q] + bv);
      }
    }
  }
}

// ---------------------------------------------------------------- attn part 1
// LDS-staged flash-style PV + online softmax stats. grid 512 WGs (8 xcd x 4 bh
// x 16 mtiles), block 512 (8 waves). QBLK=128 (16 q-rows per wave, owned
// end-to-end -> no cross-wave reduce). Per 128-s tile: K[128][64] and
// VT-tile[64][128] staged via global_load_lds (coalesced full lines), LDS
// XOR-swizzled (linear dest + pre-swizzled global source, read-side XOR).
__global__ __launch_bounds__(512) void attn_pv(
    const unsigned short* __restrict__ Q, const unsigned short* __restrict__ K,
    const unsigned short* __restrict__ VT, float2* __restrict__ Mst,
    unsigned short* __restrict__ OutPre) {
  __shared__ unsigned short Kt[128][64];   // [s][d], cols swizzled ^(row&7)
  __shared__ unsigned short Vt[64][128];   // [d][s], col16 swizzled ^(d&7)

  const int tid = threadIdx.x;
  const int w = tid >> 6, lane = tid & 63;
  const int l15 = lane & 15, l4 = lane >> 4;
  const int wgid = blockIdx.x;
  const int xcd = wgid & 7, j = wgid >> 3;          // 512 = 8 * 64
  const int bh = xcd * 4 + (j >> 4);
  const int b = bh >> 4, h = bh & 15;
  const int m0 = (j & 15) * 128;

  const unsigned short* Qp =
      Q + ((size_t)(b * 2048 + m0 + w * 16 + l15) << 10) + h * 64 + l4 * 8;
  const bf16x8 qf0 = *(const bf16x8*)Qp;
  const bf16x8 qf1 = *(const bf16x8*)(Qp + 32);

  const unsigned short* Kb = K + ((size_t)b << 21) + h * 64;
  const unsigned short* Vbh = VT + ((size_t)bh << 17);

  const int krow = lane >> 3;                  // 0..7 (row within 8-row call)
  const int kcolb = (lane & 7) ^ krow;         // pre-swizzled source col16
  const int vrow = lane >> 4;                  // 0..3

  float m_run = -3.0e38f, l_run = 0.f;
  f32x4 pv[4];
  #pragma unroll
  for (int nt = 0; nt < 4; ++nt) pv[nt] = (f32x4){0.f, 0.f, 0.f, 0.f};

  for (int t = 0; t < 16; ++t) {
    // ---- stage K tile (2 calls/wave) + V tile (2 calls/wave)
    #pragma unroll
    for (int c = 0; c < 2; ++c) {
      const int r = w * 16 + c * 8 + krow;
      gll16(Kb + ((size_t)(t * 128 + r) << 10) + kcolb * 8,
            &Kt[w * 16 + c * 8][0]);
    }
    #pragma unroll
    for (int c = 0; c < 2; ++c) {
      const int d = w * 8 + c * 4 + vrow;
      const int vc = (lane & 15) ^ (d & 7);
      gll16(Vbh + ((size_t)d << 11) + t * 128 + vc * 8,
            &Vt[w * 8 + c * 4][0]);
    }
    __syncthreads();

    // ---- QK^T from LDS (scores bf16-rounded, same path as awrite)
    unsigned int sc16[16];
    float tmax = -3.0e38f;
    #pragma unroll
    for (int sub = 0; sub < 8; ++sub) {
      const int row = sub * 16 + l15;
      const bf16x8 k0 = *(const bf16x8*)&Kt[row][(l4 ^ (l15 & 7)) * 8];
      const bf16x8 k1 = *(const bf16x8*)&Kt[row][((l4 + 4) ^ (l15 & 7)) * 8];
      f32x4 a = {0.f, 0.f, 0.f, 0.f};
      a = mfma16(k0, qf0, a);
      a = mfma16(k1, qf1, a);
      const unsigned int u0 = f2bf_u(a[0] * 0.125f);
      const unsigned int u1 = f2bf_u(a[1] * 0.125f);
      const unsigned int u2 = f2bf_u(a[2] * 0.125f);
      const unsigned int u3 = f2bf_u(a[3] * 0.125f);
      sc16[sub * 2 + 0] = (u1 << 16) | u0;
      sc16[sub * 2 + 1] = (u3 << 16) | u2;
      tmax = fmaxf(tmax, fmaxf(fmaxf(bf2f(u0), bf2f(u1)),
                               fmaxf(bf2f(u2), bf2f(u3))));
    }
    tmax = fmaxf(tmax, __shfl_xor(tmax, 16));
    tmax = fmaxf(tmax, __shfl_xor(tmax, 32));
    const float m_new = fmaxf(m_run, tmax);
    const float f = __expf(m_run - m_new);
    m_run = m_new;
    float fr[4];
    #pragma unroll
    for (int r = 0; r < 4; ++r) fr[r] = __shfl(f, l4 * 4 + r);
    #pragma unroll
    for (int nt = 0; nt < 4; ++nt) {
      pv[nt][0] *= fr[0]; pv[nt][1] *= fr[1];
      pv[nt][2] *= fr[2]; pv[nt][3] *= fr[3];
    }
    l_run *= f;

    union EF { unsigned int u4[4]; bf16x8 v; } ef[4];
    #pragma unroll
    for (int kc = 0; kc < 4; ++kc) {
      #pragma unroll
      for (int half = 0; half < 2; ++half) {
        const unsigned int p0 = sc16[(kc * 2 + half) * 2 + 0];
        const unsigned int p1 = sc16[(kc * 2 + half) * 2 + 1];
        const float e0 = __expf(bf2f(p0 & 0xffffu) - m_new);
        const float e1 = __expf(bf2f(p0 >> 16) - m_new);
        const float e2 = __expf(bf2f(p1 & 0xffffu) - m_new);
        const float e3 = __expf(bf2f(p1 >> 16) - m_new);
        l_run += e0 + e1 + e2 + e3;
        ef[kc].u4[half * 2 + 0] = pack2(e0, e1);
        ef[kc].u4[half * 2 + 1] = pack2(e2, e3);
      }
    }

    #pragma unroll
    for (int nt = 0; nt < 4; ++nt) {
      const int d = nt * 16 + l15;
      #pragma unroll
      for (int kc = 0; kc < 4; ++kc) {
        const int c16a = (kc * 4 + (l4 >> 1)) ^ (d & 7);
        const int c16b = (kc * 4 + 2 + (l4 >> 1)) ^ (d & 7);
        union { unsigned int u4[4]; bf16x8 v; } vf;
        const uint2 va = *(const uint2*)&Vt[d][c16a * 8 + (l4 & 1) * 4];
        const uint2 vb = *(const uint2*)&Vt[d][c16b * 8 + (l4 & 1) * 4];
        vf.u4[0] = va.x; vf.u4[1] = va.y; vf.u4[2] = vb.x; vf.u4[3] = vb.y;
        pv[nt] = mfma16(ef[kc].v, vf.v, pv[nt]);
      }
    }
    __syncthreads();
  }

  float lsum = l_run;
  lsum += __shfl_xor(lsum, 16);
  lsum += __shfl_xor(lsum, 32);
  const float linv = 1.0f / lsum;
  if (lane < 16)
    Mst[(size_t)bh * 2048 + m0 + w * 16 + lane] = make_float2(m_run, linv);
  #pragma unroll
  for (int r = 0; r < 4; ++r) {
    const float lq = __shfl(linv, l4 * 4 + r);
    const size_t rowoff =
        ((size_t)(b * 2048 + m0 + w * 16 + l4 * 4 + r) << 10) + h * 64;
    #pragma unroll
    for (int nt = 0; nt < 4; ++nt)
      OutPre[rowoff + nt * 16 + l15] =
          (unsigned short)f2bf_u(pv[nt][r] * lq);
  }
}

// ---------------------------------------------------------------- merged tail v2
// Blocks 0..255: out-projection GEMM (verbatim R13/R15 gemm_out, 128x128).
// Blocks 256..4351: A-writer, iso-structural with proven R13 attn_awrite:
// same 16 iterations x 128 s-cols, same 2 barriers/iter, 512B-contiguous
// flushes (2 passes of 8 rows). 4 waves: wave w covers s-chunks {2w, 2w+1}.
__global__ __launch_bounds__(256) void tail_fused(
    const unsigned short* __restrict__ Op, const unsigned short* __restrict__ WoT,
    const float* __restrict__ bo, float* __restrict__ Cout,
    const unsigned short* __restrict__ Q, const unsigned short* __restrict__ K,
    const float2* __restrict__ Mst, float* __restrict__ Aout) {
  union SharedU {
    struct { unsigned short As[128][32]; unsigned short Bs[128][32]; } g;
    float atile[16][136];
  };
  __shared__ SharedU sh;
  const int tid = threadIdx.x;
  const int lane = tid & 63, wid = tid >> 6;
  const int l15 = lane & 15, l4 = lane >> 4;

  if (blockIdx.x < 256) {
    // ---------------- out-proj GEMM: C[4096,1024] = Op * WoT^T + bo
    const int N = 1024, K_ = 1024;
    const int m0 = (blockIdx.x >> 3) * 128, n0 = (blockIdx.x & 7) * 128;
    const int wr = wid >> 1, wc = wid & 1;

    f32x4 acc[4][4];
    #pragma unroll
    for (int i = 0; i < 4; ++i)
      #pragma unroll
      for (int j = 0; j < 4; ++j) acc[i][j] = (f32x4){0.f, 0.f, 0.f, 0.f};

    for (int kt = 0; kt < (K_ >> 5); ++kt) {
      const unsigned short* G = (wid < 2) ? (Op + (size_t)m0 * K_)
                                          : (WoT + (size_t)n0 * K_);
      char* L = (wid < 2) ? (char*)&sh.g.As[0][0] : (char*)&sh.g.Bs[0][0];
      const int half = wid & 1;
      #pragma unroll
      for (int c = 0; c < 4; ++c) {
        const int off = half * 4096 + c * 1024;
        const int loff = off + lane * 16;
        const int row = loff >> 6, colb = loff & 63;
        gll16(G + (size_t)row * K_ + kt * 32 + colb / 2, L + off);
      }
      __syncthreads();
      bf16x8 af[4], bfr[4];
      #pragma unroll
      for (int i = 0; i < 4; ++i)
        af[i] = *(const bf16x8*)&sh.g.As[wr * 64 + i * 16 + l15][l4 * 8];
      #pragma unroll
      for (int j = 0; j < 4; ++j)
        bfr[j] = *(const bf16x8*)&sh.g.Bs[wc * 64 + j * 16 + l15][l4 * 8];
      #pragma unroll
      for (int i = 0; i < 4; ++i)
        #pragma unroll
        for (int j = 0; j < 4; ++j)
          acc[i][j] = mfma16(af[i], bfr[j], acc[i][j]);
      __syncthreads();
    }

    #pragma unroll
    for (int j = 0; j < 4; ++j) {
      const int col = n0 + wc * 64 + j * 16 + l15;
      const float bv = bo[col];
      #pragma unroll
      for (int i = 0; i < 4; ++i) {
        const int rowb = m0 + wr * 64 + i * 16 + l4 * 4;
        #pragma unroll
        for (int q = 0; q < 4; ++q)
          Cout[(size_t)(rowb + q) * N + col] = acc[i][j][q] + bv;
      }
    }
  } else {
    // ---------------- A-writer: 4 waves; wave w covers s-chunks {2w, 2w+1}
    const int wgid = blockIdx.x - 256;
    const int xcd = wgid & 7, j = wgid >> 3;
    const int bh = xcd * 4 + (j >> 7);
    const int b = bh >> 4, h = bh & 15;
    const int m0 = (j & 127) * 16;
    const int w = wid;  // 0..3

    const unsigned short* Qp =
        Q + ((size_t)(b * 2048 + m0 + l15) << 10) + h * 64 + l4 * 8;
    const bf16x8 qf0 = *(const bf16x8*)Qp;
    const bf16x8 qf1 = *(const bf16x8*)(Qp + 32);
    const unsigned short* Kb = K + ((size_t)b << 21) + h * 64;

    const float2 ml = Mst[(size_t)bh * 2048 + m0 + l15];
    const float mreg = ml.x, lreg = ml.y;

    float* Awg = Aout + ((size_t)bh << 22) + ((size_t)m0 << 11);
    const int frow = tid >> 5;         // flush rows 0..7 (+8 on pass 1)
    const int fcol = (tid & 31) * 4;   // 0..124

    #pragma unroll 4
    for (int i = 0; i < 16; ++i) {
      #pragma unroll
      for (int cc2 = 0; cc2 < 2; ++cc2) {
        const int cc = 2 * w + cc2;   // s-chunk 0..7 within the 128-col tile
        const unsigned short* kp =
            Kb + ((size_t)(i * 128 + cc * 16 + l15) << 10) + l4 * 8;
        const bf16x8 ck0 = *(const bf16x8*)kp;
        const bf16x8 ck1 = *(const bf16x8*)(kp + 32);
        f32x4 a = {0.f, 0.f, 0.f, 0.f};
        a = mfma16(ck0, qf0, a);
        a = mfma16(ck1, qf1, a);
        f32x4 av;
        #pragma unroll
        for (int q = 0; q < 4; ++q) {
          const float sb = bf2f(f2bf_u(a[q] * 0.125f));  // bf16-round == pv
          av[q] = __expf(sb - mreg) * lreg;
        }
        *(f32x4*)&sh.atile[l15][cc * 16 + l4 * 4] = av;
      }
      __syncthreads();
      #pragma unroll
      for (int p = 0; p < 2; ++p) {
        const int row = p * 8 + frow;
        const f32x4 v = *(const f32x4*)&sh.atile[row][fcol];
        __builtin_nontemporal_store(
            v, (f32x4*)(Awg + ((size_t)row << 11) + i * 128 + fcol));
      }
      __syncthreads();
    }
  }
}

// ---------------------------------------------------------------- launcher
extern "C" void kernel_launch(void* const* d_in, const int* in_sizes, int n_in,
                              void* d_out, int out_size, void* d_ws,
                              size_t ws_size, hipStream_t stream) {
  (void)in_sizes; (void)n_in; (void)out_size; (void)ws_size;
  const float* queries = (const float*)d_in[0];
  const float* keys    = (const float*)d_in[1];
  const float* values  = (const float*)d_in[2];
  const float* Wq = (const float*)d_in[3];  const float* bq = (const float*)d_in[4];
  const float* Wk = (const float*)d_in[5];  const float* bk = (const float*)d_in[6];
  const float* Wv = (const float*)d_in[7];  const float* bv = (const float*)d_in[8];
  const float* Wo = (const float*)d_in[9];  const float* bo = (const float*)d_in[10];

  float* out  = (float*)d_out;
  float* Aout = out + (size_t)2 * 2048 * 1024;

  char* ws = (char*)d_ws;
  unsigned short* WqT = (unsigned short*)(ws + 0);
  unsigned short* WkT = (unsigned short*)(ws + 2097152);
  unsigned short* WvT = (unsigned short*)(ws + 4194304);
  unsigned short* WoT = (unsigned short*)(ws + 6291456);
  unsigned short* Qb  = (unsigned short*)(ws + 8388608);
  unsigned short* Kbf = (unsigned short*)(ws + 16777216);
  unsigned short* VTb = (unsigned short*)(ws + 25165824);  // [bh][64][2048]
  unsigned short* Op  = (unsigned short*)(ws + 33554432);  // out_pre bf16
  float2* Mst = (float2*)(ws + 41943040);                  // [bh][2048] {m, 1/l}

  transpose_w<<<dim3(32, 32, 4), dim3(32, 8), 0, stream>>>(
      Wq, Wk, Wv, Wo, WqT, WkT, WvT, WoT);

  GemmJobs qkv;
  qkv.j[0] = {queries, WqT, bq, Qb, 0};
  qkv.j[1] = {keys,    WkT, bk, Kbf, 0};
  qkv.j[2] = {values,  WvT, bv, VTb, 2};
  gemm_qkv<<<dim3(32, 8, 3), 256, 0, stream>>>(qkv, 4096, 1024, 1024);

  attn_pv<<<dim3(512), 512, 0, stream>>>(Qb, Kbf, VTb, Mst, Op);

  tail_fused<<<dim3(4352), 256, 0, stream>>>(
      Op, WoT, bo, out, Qb, Kbf, Mst, Aout);
}

// Round 17
// 294.476 us; speedup vs baseline: 1.1553x; 1.1553x over previous
//
#include <hip/hip_runtime.h>

// B=2, L=S=2048, D_MODEL=1024, H=16, D_HEAD=64
// d_out = [out: 2*2048*1024 f32][A: 2*16*2048*2048 f32]

typedef __attribute__((ext_vector_type(8))) __bf16 bf16x8;
typedef __attribute__((ext_vector_type(4))) float f32x4;

__device__ __forceinline__ unsigned int f2bf_u(float f) {
  unsigned int u = __float_as_uint(f);
  return (u + 0x7FFFu + ((u >> 16) & 1u)) >> 16;  // RNE
}
__device__ __forceinline__ float bf2f(unsigned int h) {
  return __uint_as_float(h << 16);
}
__device__ __forceinline__ unsigned int pack2(float lo, float hi) {
  return (f2bf_u(hi) << 16) | f2bf_u(lo);
}
__device__ __forceinline__ f32x4 mfma16(bf16x8 a, bf16x8 b, f32x4 c) {
  return __builtin_amdgcn_mfma_f32_16x16x32_bf16(a, b, c, 0, 0, 0);
}
__device__ __forceinline__ void gll16(const void* g, void* l) {
  __builtin_amdgcn_global_load_lds(
      (const __attribute__((address_space(1))) unsigned int*)g,
      (__attribute__((address_space(3))) unsigned int*)l, 16, 0, 0);
}

// ---------------------------------------------------------------- transpose
// W[1024 in][1024 out] f32  ->  WT[1024 out][1024 in] bf16
__global__ __launch_bounds__(256) void transpose_w(
    const float* __restrict__ W0, const float* __restrict__ W1,
    const float* __restrict__ W2, const float* __restrict__ W3,
    unsigned short* __restrict__ T0, unsigned short* __restrict__ T1,
    unsigned short* __restrict__ T2, unsigned short* __restrict__ T3) {
  const float* W; unsigned short* T;
  switch (blockIdx.z) {
    case 0: W = W0; T = T0; break;
    case 1: W = W1; T = T1; break;
    case 2: W = W2; T = T2; break;
    default: W = W3; T = T3; break;
  }
  __shared__ float tile[32][33];
  const int tx = threadIdx.x, ty = threadIdx.y;  // 32 x 8
  const int i0 = blockIdx.x * 32, o0 = blockIdx.y * 32;
  #pragma unroll
  for (int r = 0; r < 4; ++r)
    tile[ty + 8 * r][tx] = W[(size_t)(i0 + ty + 8 * r) * 1024 + o0 + tx];
  __syncthreads();
  #pragma unroll
  for (int r = 0; r < 4; ++r)
    T[(size_t)(o0 + ty + 8 * r) * 1024 + i0 + tx] =
        (unsigned short)f2bf_u(tile[tx][ty + 8 * r]);
}

// ---------------------------------------------------------------- merged QKV GEMM
// One dispatch, grid (32, 8, 3): z selects {Q,K,V} job -> 768 WGs = 3 WG/CU.
struct GemmJob {
  const float* A;
  const unsigned short* BT;
  const float* bias;
  void* C;
  int omode;
};
struct GemmJobs { GemmJob j[3]; };

__global__ __launch_bounds__(256) void gemm_qkv(GemmJobs jobs, int M, int N, int K) {
  const GemmJob jb = jobs.j[blockIdx.z];
  __shared__ unsigned short As[128][40];
  __shared__ unsigned short Bs[128][32];
  const int tid = threadIdx.x;
  const int lane = tid & 63, wid = tid >> 6;
  const int l15 = lane & 15, l4 = lane >> 4;
  const int m0 = blockIdx.x * 128, n0 = blockIdx.y * 128;
  const int wr = wid >> 1, wc = wid & 1;

  f32x4 acc[4][4];
  #pragma unroll
  for (int i = 0; i < 4; ++i)
    #pragma unroll
    for (int j = 0; j < 4; ++j) acc[i][j] = (f32x4){0.f, 0.f, 0.f, 0.f};

  const int nk = K >> 5;
  for (int kt = 0; kt < nk; ++kt) {
    // A f32 -> bf16: all 256 threads, 4 chunks each (chunk-coalesced 128B/row)
    #pragma unroll
    for (int c = 0; c < 4; ++c) {
      const int chunk = c * 256 + tid;
      const int row = chunk >> 3, col4 = chunk & 7;
      const float4 f = *(const float4*)(jb.A +
                                        (size_t)(m0 + row) * K + kt * 32 + col4 * 4);
      ushort4 o;
      o.x = (unsigned short)f2bf_u(f.x);
      o.y = (unsigned short)f2bf_u(f.y);
      o.z = (unsigned short)f2bf_u(f.z);
      o.w = (unsigned short)f2bf_u(f.w);
      *(ushort4*)&As[row][col4 * 4] = o;
    }
    // B bf16 via global_load_lds: all 4 waves, 2 calls each
    #pragma unroll
    for (int c = 0; c < 2; ++c) {
      const int off = wid * 2048 + c * 1024;
      const int loff = off + lane * 16;
      const int row = loff >> 6, colb = loff & 63;
      gll16(jb.BT + (size_t)(n0 + row) * K + kt * 32 + colb / 2,
            (char*)&Bs[0][0] + off);
    }
    __syncthreads();
    bf16x8 af[4], bfr[4];
    #pragma unroll
    for (int i = 0; i < 4; ++i)
      af[i] = *(const bf16x8*)&As[wr * 64 + i * 16 + l15][l4 * 8];
    #pragma unroll
    for (int j = 0; j < 4; ++j)
      bfr[j] = *(const bf16x8*)&Bs[wc * 64 + j * 16 + l15][l4 * 8];
    #pragma unroll
    for (int i = 0; i < 4; ++i)
      #pragma unroll
      for (int j = 0; j < 4; ++j)
        acc[i][j] = mfma16(af[i], bfr[j], acc[i][j]);
    __syncthreads();
  }

  #pragma unroll
  for (int j = 0; j < 4; ++j) {
    const int col = n0 + wc * 64 + j * 16 + l15;
    const float bv = jb.bias[col];
    #pragma unroll
    for (int i = 0; i < 4; ++i) {
      const int rowb = m0 + wr * 64 + i * 16 + l4 * 4;
      if (jb.omode == 2) {
        const int bq = rowb >> 11, sq = rowb & 2047;
        const int hq = col >> 6, dq = col & 63;
        ushort4 o;
        o.x = (unsigned short)f2bf_u(acc[i][j][0] + bv);
        o.y = (unsigned short)f2bf_u(acc[i][j][1] + bv);
        o.z = (unsigned short)f2bf_u(acc[i][j][2] + bv);
        o.w = (unsigned short)f2bf_u(acc[i][j][3] + bv);
        *(ushort4*)((unsigned short*)jb.C +
                    ((size_t)((bq * 16 + hq) * 64 + dq) << 11) + sq) = o;
      } else {
        #pragma unroll
        for (int q = 0; q < 4; ++q)
          ((unsigned short*)jb.C)[(size_t)(rowb + q) * N + col] =
              (unsigned short)f2bf_u(acc[i][j][q] + bv);
      }
    }
  }
}

// ---------------------------------------------------------------- out-proj GEMM
// 128x64 tiles -> grid (32,16) = 512 WGs = 2 WG/CU (occupancy lever).
// 4 waves, each owns 32 rows x 64 cols (acc[2][4]). A bf16, C f32.
__global__ __launch_bounds__(256) void gemm_out(
    const unsigned short* __restrict__ Ap, const unsigned short* __restrict__ BT,
    const float* __restrict__ bias, float* __restrict__ Cp,
    int M, int N, int K) {
  __shared__ unsigned short As[128][32];
  __shared__ unsigned short Bs[64][32];
  const int tid = threadIdx.x;
  const int lane = tid & 63, w = tid >> 6;
  const int l15 = lane & 15, l4 = lane >> 4;
  const int m0 = blockIdx.x * 128, n0 = blockIdx.y * 64;

  f32x4 acc[2][4];
  #pragma unroll
  for (int i = 0; i < 2; ++i)
    #pragma unroll
    for (int j = 0; j < 4; ++j) acc[i][j] = (f32x4){0.f, 0.f, 0.f, 0.f};

  const int nk = K >> 5;
  for (int kt = 0; kt < nk; ++kt) {
    #pragma unroll
    for (int c = 0; c < 2; ++c) {  // A: 2 calls/wave (8KB total)
      const int off = (w * 2 + c) * 1024;
      const int loff = off + lane * 16;
      const int row = loff >> 6, colb = loff & 63;
      gll16(Ap + (size_t)(m0 + row) * K + kt * 32 + colb / 2,
            (char*)&As[0][0] + off);
    }
    {  // B: 1 call/wave (4KB total)
      const int off = w * 1024;
      const int loff = off + lane * 16;
      const int row = loff >> 6, colb = loff & 63;
      gll16(BT + (size_t)(n0 + row) * K + kt * 32 + colb / 2,
            (char*)&Bs[0][0] + off);
    }
    __syncthreads();
    bf16x8 af[2], bfr[4];
    #pragma unroll
    for (int i = 0; i < 2; ++i)
      af[i] = *(const bf16x8*)&As[w * 32 + i * 16 + l15][l4 * 8];
    #pragma unroll
    for (int j = 0; j < 4; ++j)
      bfr[j] = *(const bf16x8*)&Bs[j * 16 + l15][l4 * 8];
    #pragma unroll
    for (int i = 0; i < 2; ++i)
      #pragma unroll
      for (int j = 0; j < 4; ++j)
        acc[i][j] = mfma16(af[i], bfr[j], acc[i][j]);
    __syncthreads();
  }

  #pragma unroll
  for (int j = 0; j < 4; ++j) {
    const int col = n0 + j * 16 + l15;
    const float bv = bias[col];
    #pragma unroll
    for (int i = 0; i < 2; ++i) {
      const int rowb = m0 + w * 32 + i * 16 + l4 * 4;
      #pragma unroll
      for (int q = 0; q < 4; ++q)
        Cp[(size_t)(rowb + q) * N + col] = acc[i][j][q] + bv;
    }
  }
}

// ---------------------------------------------------------------- attn part 1
// LDS-staged flash PV. grid 512 WGs (8 xcd x 4 bh x 16 mtiles), block 256
// (4 waves x 32 q-rows: each K/V fragment load feeds TWO MFMAs -> LDS read
// traffic halves vs 8x16). Scores/stats bitwise-identical to the 8-wave
// version (same K operands, same per-16-row MFMA grouping, same acc order).
__global__ __launch_bounds__(256) void attn_pv(
    const unsigned short* __restrict__ Q, const unsigned short* __restrict__ K,
    const unsigned short* __restrict__ VT, float2* __restrict__ Mst,
    unsigned short* __restrict__ OutPre) {
  __shared__ unsigned short Kt[128][64];   // [s][d], cols swizzled ^(row&7)
  __shared__ unsigned short Vt[64][128];   // [d][s], col16 swizzled ^(d&7)

  const int tid = threadIdx.x;
  const int w = tid >> 6, lane = tid & 63;
  const int l15 = lane & 15, l4 = lane >> 4;
  const int wgid = blockIdx.x;
  const int xcd = wgid & 7, j = wgid >> 3;          // 512 = 8 * 64
  const int bh = xcd * 4 + (j >> 4);
  const int b = bh >> 4, h = bh & 15;
  const int m0 = (j & 15) * 128;
  const int base = w * 32;                           // this wave's 32 q-rows

  bf16x8 qf0[2], qf1[2];
  #pragma unroll
  for (int f = 0; f < 2; ++f) {
    const unsigned short* Qp =
        Q + ((size_t)(b * 2048 + m0 + base + f * 16 + l15) << 10) + h * 64 + l4 * 8;
    qf0[f] = *(const bf16x8*)Qp;
    qf1[f] = *(const bf16x8*)(Qp + 32);
  }

  const unsigned short* Kb = K + ((size_t)b << 21) + h * 64;
  const unsigned short* Vbh = VT + ((size_t)bh << 17);

  const int krow = lane >> 3;                  // 0..7 (row within 8-row call)
  const int kcolb = (lane & 7) ^ krow;         // pre-swizzled source col16
  const int vrow = lane >> 4;                  // 0..3

  float m_run[2] = {-3.0e38f, -3.0e38f};
  float l_run[2] = {0.f, 0.f};
  f32x4 pv[2][4];
  #pragma unroll
  for (int f = 0; f < 2; ++f)
    #pragma unroll
    for (int nt = 0; nt < 4; ++nt) pv[f][nt] = (f32x4){0.f, 0.f, 0.f, 0.f};

  for (int t = 0; t < 16; ++t) {
    // ---- stage K tile (4 calls/wave) + V tile (4 calls/wave)
    #pragma unroll
    for (int c = 0; c < 4; ++c) {
      const int r = base + c * 8 + krow;
      gll16(Kb + ((size_t)(t * 128 + r) << 10) + kcolb * 8,
            &Kt[base + c * 8][0]);
    }
    #pragma unroll
    for (int c = 0; c < 4; ++c) {
      const int d = w * 16 + c * 4 + vrow;
      const int vc = (lane & 15) ^ (d & 7);
      gll16(Vbh + ((size_t)d << 11) + t * 128 + vc * 8,
            &Vt[w * 16 + c * 4][0]);
    }
    __syncthreads();

    // ---- QK^T from LDS: K-frag loaded once, feeds both Q-frags
    unsigned int sc16[2][16];
    float tmax[2] = {-3.0e38f, -3.0e38f};
    #pragma unroll
    for (int sub = 0; sub < 8; ++sub) {
      const int row = sub * 16 + l15;
      const bf16x8 k0 = *(const bf16x8*)&Kt[row][(l4 ^ (l15 & 7)) * 8];
      const bf16x8 k1 = *(const bf16x8*)&Kt[row][((l4 + 4) ^ (l15 & 7)) * 8];
      #pragma unroll
      for (int f = 0; f < 2; ++f) {
        f32x4 a = {0.f, 0.f, 0.f, 0.f};
        a = mfma16(k0, qf0[f], a);
        a = mfma16(k1, qf1[f], a);
        const unsigned int u0 = f2bf_u(a[0] * 0.125f);
        const unsigned int u1 = f2bf_u(a[1] * 0.125f);
        const unsigned int u2 = f2bf_u(a[2] * 0.125f);
        const unsigned int u3 = f2bf_u(a[3] * 0.125f);
        sc16[f][sub * 2 + 0] = (u1 << 16) | u0;
        sc16[f][sub * 2 + 1] = (u3 << 16) | u2;
        tmax[f] = fmaxf(tmax[f], fmaxf(fmaxf(bf2f(u0), bf2f(u1)),
                                       fmaxf(bf2f(u2), bf2f(u3))));
      }
    }
    #pragma unroll
    for (int f = 0; f < 2; ++f) {
      float tm = tmax[f];
      tm = fmaxf(tm, __shfl_xor(tm, 16));
      tm = fmaxf(tm, __shfl_xor(tm, 32));
      const float m_new = fmaxf(m_run[f], tm);
      const float fs = __expf(m_run[f] - m_new);
      m_run[f] = m_new;
      float fr[4];
      #pragma unroll
      for (int r = 0; r < 4; ++r) fr[r] = __shfl(fs, l4 * 4 + r);
      #pragma unroll
      for (int nt = 0; nt < 4; ++nt) {
        pv[f][nt][0] *= fr[0]; pv[f][nt][1] *= fr[1];
        pv[f][nt][2] *= fr[2]; pv[f][nt][3] *= fr[3];
      }
      l_run[f] *= fs;
    }

    union EF { unsigned int u4[4]; bf16x8 v; } ef[2][4];
    #pragma unroll
    for (int f = 0; f < 2; ++f)
      #pragma unroll
      for (int kc = 0; kc < 4; ++kc)
        #pragma unroll
        for (int half = 0; half < 2; ++half) {
          const unsigned int p0 = sc16[f][(kc * 2 + half) * 2 + 0];
          const unsigned int p1 = sc16[f][(kc * 2 + half) * 2 + 1];
          const float e0 = __expf(bf2f(p0 & 0xffffu) - m_run[f]);
          const float e1 = __expf(bf2f(p0 >> 16) - m_run[f]);
          const float e2 = __expf(bf2f(p1 & 0xffffu) - m_run[f]);
          const float e3 = __expf(bf2f(p1 >> 16) - m_run[f]);
          l_run[f] += e0 + e1 + e2 + e3;
          ef[f][kc].u4[half * 2 + 0] = pack2(e0, e1);
          ef[f][kc].u4[half * 2 + 1] = pack2(e2, e3);
        }

    // ---- PV: V-frag loaded once, feeds both Q-frags
    #pragma unroll
    for (int nt = 0; nt < 4; ++nt) {
      const int d = nt * 16 + l15;
      #pragma unroll
      for (int kc = 0; kc < 4; ++kc) {
        const int c16a = (kc * 4 + (l4 >> 1)) ^ (d & 7);
        const int c16b = (kc * 4 + 2 + (l4 >> 1)) ^ (d & 7);
        union { unsigned int u4[4]; bf16x8 v; } vf;
        const uint2 va = *(const uint2*)&Vt[d][c16a * 8 + (l4 & 1) * 4];
        const uint2 vb = *(const uint2*)&Vt[d][c16b * 8 + (l4 & 1) * 4];
        vf.u4[0] = va.x; vf.u4[1] = va.y; vf.u4[2] = vb.x; vf.u4[3] = vb.y;
        pv[0][nt] = mfma16(ef[0][kc].v, vf.v, pv[0][nt]);
        pv[1][nt] = mfma16(ef[1][kc].v, vf.v, pv[1][nt]);
      }
    }
    __syncthreads();
  }

  float linv[2];
  #pragma unroll
  for (int f = 0; f < 2; ++f) {
    float ls = l_run[f];
    ls += __shfl_xor(ls, 16);
    ls += __shfl_xor(ls, 32);
    linv[f] = 1.0f / ls;
  }
  if (lane < 16) {
    Mst[(size_t)bh * 2048 + m0 + base + lane] = make_float2(m_run[0], linv[0]);
    Mst[(size_t)bh * 2048 + m0 + base + 16 + lane] =
        make_float2(m_run[1], linv[1]);
  }
  #pragma unroll
  for (int f = 0; f < 2; ++f)
    #pragma unroll
    for (int r = 0; r < 4; ++r) {
      const float lq = __shfl(linv[f], l4 * 4 + r);
      const size_t rowoff =
          ((size_t)(b * 2048 + m0 + base + f * 16 + l4 * 4 + r) << 10) + h * 64;
      #pragma unroll
      for (int nt = 0; nt < 4; ++nt)
        OutPre[rowoff + nt * 16 + l15] =
            (unsigned short)f2bf_u(pv[f][nt][r] * lq);
    }
}

// ---------------------------------------------------------------- attn part 2
// Pure A-writer (proven: ~7 TB/s): recompute scores (bitwise-identical
// bf16-round path), exp with stats from Mst, full-line nontemporal stores.
__global__ __launch_bounds__(512) void attn_awrite(
    const unsigned short* __restrict__ Q, const unsigned short* __restrict__ K,
    const float2* __restrict__ Mst, float* __restrict__ Aout) {
  __shared__ float atile[16][136];
  const int tid = threadIdx.x;
  const int w = tid >> 6, lane = tid & 63;
  const int l15 = lane & 15, l4 = lane >> 4;
  const int wgid = blockIdx.x;
  const int xcd = wgid & 7, j = wgid >> 3;
  const int bh = xcd * 4 + (j >> 7);
  const int b = bh >> 4, h = bh & 15;
  const int m0 = (j & 127) * 16;

  const unsigned short* Qp =
      Q + ((size_t)(b * 2048 + m0 + l15) << 10) + h * 64 + l4 * 8;
  const bf16x8 qf0 = *(const bf16x8*)Qp;
  const bf16x8 qf1 = *(const bf16x8*)(Qp + 32);
  const unsigned short* Kb = K + ((size_t)b << 21) + h * 64;

  const float2 ml = Mst[(size_t)bh * 2048 + m0 + l15];
  const float mreg = ml.x, lreg = ml.y;

  float* Awg = Aout + ((size_t)bh << 22) + ((size_t)m0 << 11);
  const int frow = tid >> 5;         // flush: 0..15
  const int fcol = (tid & 31) * 4;   // 0..124

  const unsigned short* kp0 = Kb + ((size_t)(w * 16 + l15) << 10) + l4 * 8;
  bf16x8 ck0 = *(const bf16x8*)kp0;
  bf16x8 ck1 = *(const bf16x8*)(kp0 + 32);
  #pragma unroll
  for (int i = 0; i < 16; ++i) {
    bf16x8 nk0, nk1;
    if (i < 15) {
      const unsigned short* kp =
          Kb + ((size_t)((i + 1) * 128 + w * 16 + l15) << 10) + l4 * 8;
      nk0 = *(const bf16x8*)kp;
      nk1 = *(const bf16x8*)(kp + 32);
    }
    f32x4 a = {0.f, 0.f, 0.f, 0.f};
    a = mfma16(ck0, qf0, a);
    a = mfma16(ck1, qf1, a);
    ck0 = nk0;
    ck1 = nk1;
    f32x4 av;
    #pragma unroll
    for (int q = 0; q < 4; ++q) {
      const float sb = bf2f(f2bf_u(a[q] * 0.125f));  // bf16-round == pv path
      av[q] = __expf(sb - mreg) * lreg;
    }
    *(f32x4*)&atile[l15][w * 16 + l4 * 4] = av;
    __syncthreads();
    const f32x4 v = *(const f32x4*)&atile[frow][fcol];
    __builtin_nontemporal_store(
        v, (f32x4*)(Awg + ((size_t)frow << 11) + i * 128 + fcol));
    __syncthreads();
  }
}

// ---------------------------------------------------------------- launcher
extern "C" void kernel_launch(void* const* d_in, const int* in_sizes, int n_in,
                              void* d_out, int out_size, void* d_ws,
                              size_t ws_size, hipStream_t stream) {
  (void)in_sizes; (void)n_in; (void)out_size; (void)ws_size;
  const float* queries = (const float*)d_in[0];
  const float* keys    = (const float*)d_in[1];
  const float* values  = (const float*)d_in[2];
  const float* Wq = (const float*)d_in[3];  const float* bq = (const float*)d_in[4];
  const float* Wk = (const float*)d_in[5];  const float* bk = (const float*)d_in[6];
  const float* Wv = (const float*)d_in[7];  const float* bv = (const float*)d_in[8];
  const float* Wo = (const float*)d_in[9];  const float* bo = (const float*)d_in[10];

  float* out  = (float*)d_out;
  float* Aout = out + (size_t)2 * 2048 * 1024;

  char* ws = (char*)d_ws;
  unsigned short* WqT = (unsigned short*)(ws + 0);
  unsigned short* WkT = (unsigned short*)(ws + 2097152);
  unsigned short* WvT = (unsigned short*)(ws + 4194304);
  unsigned short* WoT = (unsigned short*)(ws + 6291456);
  unsigned short* Qb  = (unsigned short*)(ws + 8388608);
  unsigned short* Kbf = (unsigned short*)(ws + 16777216);
  unsigned short* VTb = (unsigned short*)(ws + 25165824);  // [bh][64][2048]
  unsigned short* Op  = (unsigned short*)(ws + 33554432);  // out_pre bf16
  float2* Mst = (float2*)(ws + 41943040);                  // [bh][2048] {m, 1/l}

  transpose_w<<<dim3(32, 32, 4), dim3(32, 8), 0, stream>>>(
      Wq, Wk, Wv, Wo, WqT, WkT, WvT, WoT);

  GemmJobs qkv;
  qkv.j[0] = {queries, WqT, bq, Qb, 0};
  qkv.j[1] = {keys,    WkT, bk, Kbf, 0};
  qkv.j[2] = {values,  WvT, bv, VTb, 2};
  gemm_qkv<<<dim3(32, 8, 3), 256, 0, stream>>>(qkv, 4096, 1024, 1024);

  attn_pv<<<dim3(512), 256, 0, stream>>>(Qb, Kbf, VTb, Mst, Op);
  attn_awrite<<<dim3(4096), 512, 0, stream>>>(Qb, Kbf, Mst, Aout);

  gemm_out<<<dim3(32, 16), 256, 0, stream>>>(
      Op, WoT, bo, out, 4096, 1024, 1024);
}